// Round 19
// baseline (167.385 us; speedup 1.0000x reference)
//
#include <hip/hip_runtime.h>

#define D 64
#define K 1024
#define NROWS (32 * 4096)
#define NELEM (NROWS * D)
#define COMMIT 0.25f
#define DELTA 1.2e-4f

typedef __attribute__((ext_vector_type(8))) short short8v;   // 8 bf16
typedef __attribute__((ext_vector_type(4))) float f32x4;
typedef unsigned long long u64;

#define FORSLOT8(M) M(0) M(1) M(2) M(3) M(4) M(5) M(6) M(7)

static __device__ __forceinline__ float fence(float v) {
    asm("" : "+v"(v));
    return v;
}

// f32 -> bf16 bits, round-to-nearest-even (finite inputs only).
static __device__ __forceinline__ unsigned short f2bf(float f) {
    unsigned u = __float_as_uint(f);
    return (unsigned short)((u + 0x7FFFu + ((u >> 16) & 1u)) >> 16);
}

// numpy pairwise_sum for n=64: 8 accumulators stride 8, then pairwise tree.
static __device__ __forceinline__ float np_sumsq64(const float* __restrict__ e) {
    float r[8];
#pragma unroll
    for (int j = 0; j < 8; ++j) r[j] = fence(e[j] * e[j]);
#pragma unroll
    for (int t = 1; t < 8; ++t)
#pragma unroll
        for (int j = 0; j < 8; ++j) r[j] = r[j] + fence(e[8 * t + j] * e[8 * t + j]);
    return ((r[0] + r[1]) + (r[2] + r[3])) + ((r[4] + r[5]) + (r[6] + r[7]));
}

// Bit-exact reference score: s = fl( fl(R+N) - 2*dot ), dot = ascending-i
// sequential FMA chain (validated absmax=0 in R2..R18).
static __device__ __forceinline__ float exact_score(
    const float* __restrict__ xrow, const float* __restrict__ erow, float R,
    float N) {
    float a = 0.0f;
#pragma unroll
    for (int i = 0; i < D; ++i) a = __builtin_fmaf(xrow[i], erow[i], a);
    return (R + N) - 2.0f * a;
}

// ---------------- Kernel 1: embedding prep (bf16 + norms) ----------------
__global__ void prep_emb_kernel(const float* __restrict__ emb,
                                float* __restrict__ enorm,
                                unsigned short* __restrict__ e_hi,
                                float* __restrict__ loss_slot) {
    int k = blockIdx.x * blockDim.x + threadIdx.x;
    if (k == 0) *loss_slot = 0.0f;
    if (k >= K) return;
    enorm[k] = np_sumsq64(emb + k * D);
    const float* e = emb + k * D;
#pragma unroll
    for (int i = 0; i < D; ++i) e_hi[k * D + i] = f2bf(e[i]);
}

// ---------------- Kernel 2: 2-pass single-product MFMA argmin, 32-row block -
// EXACT R16 algorithm (validated 109.9us / absmax=0); only change: block owns
// 32 rows (2 row-tiles/wave, was 4). Rationale (R13-R18 counters): occupancy
// tracks arch-VGPR + ~64-96 hidden AGPRs from concurrently-live MFMA acc
// quads; both pipes run at computed busy time while wall is 4x -> concurrency
// shortfall. Halving per-wave state (A-frags 16, mA 8, thr 8, half the acc
// quads) is the only lever that has moved this kernel (R16's -50us came with
// VGPR 88->56). Cost: B-traffic x2 (~31us L2/CU) -- overlappable if waves x2.
__global__ __launch_bounds__(256, 1) void argmin_kernel(
    const float* __restrict__ x, const float* __restrict__ emb,
    const float* __restrict__ enorm, const unsigned short* __restrict__ e_hi,
    float* __restrict__ out_q, float* __restrict__ idx_f,
    float* __restrict__ loss_slot) {
    const int l = threadIdx.x & 63;
    const int w = threadIdx.x >> 6;
    const int rowbase = blockIdx.x * 32;
    const int cbase = w * 256;

    __shared__ float wminA[4][32];
    __shared__ float gmin[32];
    __shared__ int cnt[32];
    __shared__ int clist[32][8];
    __shared__ int bidx[32];
    __shared__ float wsum[4];

    // ---- A-fragments: bf16(x), named SSA short8v. Layout (16x16x32):
    // row = l&15, k = h*32 + (l>>4)*8 + i; B uses the same permutation.
#define DECL_A(rt, h)                                                       \
    short8v Ahi_##rt##_##h;                                                 \
    { const float* p = x + (size_t)(rowbase + rt * 16 + (l & 15)) * D +     \
                       h * 32 + (l >> 4) * 8;                               \
      float4 q0 = *(const float4*)p, q1 = *(const float4*)(p + 4);          \
      Ahi_##rt##_##h[0] = (short)f2bf(q0.x);                                \
      Ahi_##rt##_##h[1] = (short)f2bf(q0.y);                                \
      Ahi_##rt##_##h[2] = (short)f2bf(q0.z);                                \
      Ahi_##rt##_##h[3] = (short)f2bf(q0.w);                                \
      Ahi_##rt##_##h[4] = (short)f2bf(q1.x);                                \
      Ahi_##rt##_##h[5] = (short)f2bf(q1.y);                                \
      Ahi_##rt##_##h[6] = (short)f2bf(q1.z);                                \
      Ahi_##rt##_##h[7] = (short)f2bf(q1.w); }
    DECL_A(0, 0) DECL_A(0, 1) DECL_A(1, 0) DECL_A(1, 1)

    const int koff = (l >> 4) * 8;
    const unsigned short* __restrict__ bh =
        e_hi + (size_t)(cbase + (l & 15)) * D + koff;
    const float* __restrict__ bn = enorm + cbase + (l & 15);

#define LOADT(H0, H1, NN, off)                                              \
    H0 = *(const short8v*)(bh + (size_t)(off) * 1024);                      \
    H1 = *(const short8v*)(bh + (size_t)(off) * 1024 + 32);                 \
    NN = bn[(off) * 16];

    // slot s = rt*4 + r maps to row (s/4)*16 + (l>>4)*4 + (s%4); rows 0..31
#define SLOTROW(s) (((s) / 4) * 16 + (l >> 4) * 4 + ((s) % 4))

    // =================== PASS A: fminf min, ping-pong ===================
#define DECL_MA(s) float mA_##s = 3.402823466e+38f;
    FORSLOT8(DECL_MA)
#define MFMA2A(rt, sA, sB, sC, sD)                                          \
    { f32x4 acc = {0.f, 0.f, 0.f, 0.f};                                     \
      acc = __builtin_amdgcn_mfma_f32_16x16x32_bf16(Ahi_##rt##_0, Bhi0, acc, 0, 0, 0); \
      acc = __builtin_amdgcn_mfma_f32_16x16x32_bf16(Ahi_##rt##_1, Bhi1, acc, 0, 0, 0); \
      mA_##sA = fminf(mA_##sA, __builtin_fmaf(-2.0f, acc[0], Nc));          \
      mA_##sB = fminf(mA_##sB, __builtin_fmaf(-2.0f, acc[1], Nc));          \
      mA_##sC = fminf(mA_##sC, __builtin_fmaf(-2.0f, acc[2], Nc));          \
      mA_##sD = fminf(mA_##sD, __builtin_fmaf(-2.0f, acc[3], Nc)); }
#define TILEA(H0, H1, NN)                                                   \
    { const short8v Bhi0 = H0, Bhi1 = H1;                                   \
      const float Nc = NN;                                                  \
      MFMA2A(0, 0, 1, 2, 3) MFMA2A(1, 4, 5, 6, 7) }
    {
        short8v pH0, pH1, qH0, qH1;
        float pN, qN;
        LOADT(pH0, pH1, pN, 0)
        for (int nt = 0; nt < 16; nt += 2) {
            LOADT(qH0, qH1, qN, nt + 1)
            TILEA(pH0, pH1, pN)
            const int nxt = (nt + 2 < 16) ? nt + 2 : 15;
            LOADT(pH0, pH1, pN, nxt)
            TILEA(qH0, qH1, qN)
        }
    }
    // C/D layout: col = l&15 (code), row-group = 16 contiguous lanes.
#define BFA(s)                                                              \
    mA_##s = fminf(mA_##s, __shfl_xor(mA_##s, 1));                          \
    mA_##s = fminf(mA_##s, __shfl_xor(mA_##s, 2));                          \
    mA_##s = fminf(mA_##s, __shfl_xor(mA_##s, 4));                          \
    mA_##s = fminf(mA_##s, __shfl_xor(mA_##s, 8));
    FORSLOT8(BFA)
#define WRA(s) if ((l & 15) == 0) wminA[w][SLOTROW(s)] = mA_##s;
    FORSLOT8(WRA)
    __syncthreads();
    if (threadIdx.x < 32) {
        gmin[threadIdx.x] =
            fminf(fminf(wminA[0][threadIdx.x], wminA[1][threadIdx.x]),
                  fminf(wminA[2][threadIdx.x], wminA[3][threadIdx.x]));
        cnt[threadIdx.x] = 0;
    }
    __syncthreads();

    // =================== PASS B: candidate collection ===================
#define DECL_T(s) const float thr_##s = gmin[SLOTROW(s)] + DELTA;
    FORSLOT8(DECL_T)
#define CHK(s, tval)                                                        \
    { float t = __builtin_fmaf(-2.0f, (tval), Nc);                          \
      if (t <= thr_##s) {                                                   \
          int row = SLOTROW(s);                                             \
          int pos = atomicAdd(&cnt[row], 1);                                \
          if (pos < 8) clist[row][pos] = code;                              \
      } }
#define MFMA2B(rt, sA, sB, sC, sD)                                          \
    { f32x4 acc = {0.f, 0.f, 0.f, 0.f};                                     \
      acc = __builtin_amdgcn_mfma_f32_16x16x32_bf16(Ahi_##rt##_0, Bhi0, acc, 0, 0, 0); \
      acc = __builtin_amdgcn_mfma_f32_16x16x32_bf16(Ahi_##rt##_1, Bhi1, acc, 0, 0, 0); \
      CHK(sA, acc[0]) CHK(sB, acc[1]) CHK(sC, acc[2]) CHK(sD, acc[3]) }
#define TILEB(H0, H1, NN, NT)                                               \
    { const short8v Bhi0 = H0, Bhi1 = H1;                                   \
      const float Nc = NN;                                                  \
      const int code = cbase + (l & 15) + (NT) * 16;                        \
      MFMA2B(0, 0, 1, 2, 3) MFMA2B(1, 4, 5, 6, 7) }
    {
        short8v pH0, pH1, qH0, qH1;
        float pN, qN;
        LOADT(pH0, pH1, pN, 0)
        for (int nt = 0; nt < 16; nt += 2) {
            LOADT(qH0, qH1, qN, nt + 1)
            TILEB(pH0, pH1, pN, nt)
            const int nxt = (nt + 2 < 16) ? nt + 2 : 15;
            LOADT(pH0, pH1, pN, nxt)
            TILEB(qH0, qH1, qN, nt + 1)
        }
    }
    __syncthreads();

    // ---- select / rescue (1 thread per row), bit-exact final answer ----
    if (threadIdx.x < 32) {
        const int row = threadIdx.x;
        const int n = cnt[row];
        int bk;
        if (n == 1) {
            bk = clist[row][0];
        } else {
            const float* xrow = x + (size_t)(rowbase + row) * D;
            const float R = np_sumsq64(xrow);
            float sb = 3.402823466e+38f;
            int kb = 0x7fffffff;
            if (n <= 8) {
                for (int i = 0; i < n; ++i) {
                    int c = clist[row][i];
                    float s = exact_score(xrow, emb + ((size_t)c << 6), R,
                                          enorm[c]);
                    if (s < sb || (s == sb && c < kb)) { sb = s; kb = c; }
                }
            } else {  // clist overflow: full exact scan (essentially never)
                for (int c = 0; c < K; ++c) {
                    float s = exact_score(xrow, emb + ((size_t)c << 6), R,
                                          enorm[c]);
                    if (s < sb || (s == sb && c < kb)) { sb = s; kb = c; }
                }
            }
            bk = kb;
        }
        bidx[row] = bk;
        idx_f[rowbase + row] = (float)bk;
    }
    __syncthreads();

    // ---- fused epilogue: gather + straight-through + loss ----
    {
        const int row = threadIdx.x >> 3;          // 8 threads per row
        const int d0 = (threadIdx.x & 7) * 8;      // 8 floats each
        const int bk = bidx[row];
        const float4* xq = (const float4*)(x + (size_t)(rowbase + row) * D + d0);
        const float4* eq = (const float4*)(emb + ((size_t)bk << 6) + d0);
        float4* oq = (float4*)(out_q + (size_t)(rowbase + row) * D + d0);
        float lsum = 0.f;
#pragma unroll
        for (int i = 0; i < 2; ++i) {
            float4 xv = xq[i];
            float4 ev = eq[i];
            float dx = ev.x - xv.x, dy = ev.y - xv.y, dz = ev.z - xv.z,
                  dw = ev.w - xv.w;
            float4 o;
            o.x = xv.x + dx;
            o.y = xv.y + dy;
            o.z = xv.z + dz;
            o.w = xv.w + dw;
            oq[i] = o;
            lsum = __builtin_fmaf(dx, dx, lsum);
            lsum = __builtin_fmaf(dy, dy, lsum);
            lsum = __builtin_fmaf(dz, dz, lsum);
            lsum = __builtin_fmaf(dw, dw, lsum);
        }
#pragma unroll
        for (int o = 32; o > 0; o >>= 1) lsum += __shfl_xor(lsum, o);
        if (l == 0) wsum[w] = lsum;
        __syncthreads();
        if (threadIdx.x == 0)
            atomicAdd(loss_slot, ((wsum[0] + wsum[1]) + (wsum[2] + wsum[3])) *
                                     ((1.0f + COMMIT) / (float)NELEM));
    }
}

extern "C" void kernel_launch(void* const* d_in, const int* in_sizes, int n_in,
                              void* d_out, int out_size, void* d_ws,
                              size_t ws_size, hipStream_t stream) {
    const float* x = (const float*)d_in[0];    // [32,4096,64] f32
    const float* emb = (const float*)d_in[1];  // [1024,64] f32

    float* out = (float*)d_out;
    float* loss_slot = out;              // out[0]
    float* out_q = out + 1;              // out[1 .. 1+NELEM)
    float* idx_f = out + 1 + NELEM;      // indices as f32

    // workspace layout (16B-aligned slabs)
    float* enorm = (float*)d_ws;                                    // 4 KB
    unsigned short* e_hi = (unsigned short*)((char*)d_ws + 4096);   // 128 KB

    prep_emb_kernel<<<(K + 255) / 256, 256, 0, stream>>>(emb, enorm, e_hi,
                                                         loss_slot);
    argmin_kernel<<<NROWS / 32, 256, 0, stream>>>(x, emb, enorm, e_hi, out_q,
                                                  idx_f, loss_slot);
}

// Round 20
// 119.080 us; speedup vs baseline: 1.4057x; 1.4057x over previous
//
#include <hip/hip_runtime.h>

#define D 64
#define K 1024
#define NROWS (32 * 4096)
#define NELEM (NROWS * D)
#define COMMIT 0.25f
#define DELTA 1.2e-4f

typedef __attribute__((ext_vector_type(8))) short short8v;   // 8 bf16
typedef __attribute__((ext_vector_type(4))) float f32x4;
typedef unsigned long long u64;

#define FORSLOT(M) M(0) M(1) M(2) M(3) M(4) M(5) M(6) M(7) \
                   M(8) M(9) M(10) M(11) M(12) M(13) M(14) M(15)

static __device__ __forceinline__ float fence(float v) {
    asm("" : "+v"(v));
    return v;
}

// f32 -> bf16 bits, round-to-nearest-even (finite inputs only).
static __device__ __forceinline__ unsigned short f2bf(float f) {
    unsigned u = __float_as_uint(f);
    return (unsigned short)((u + 0x7FFFu + ((u >> 16) & 1u)) >> 16);
}

// numpy pairwise_sum for n=64: 8 accumulators stride 8, then pairwise tree.
static __device__ __forceinline__ float np_sumsq64(const float* __restrict__ e) {
    float r[8];
#pragma unroll
    for (int j = 0; j < 8; ++j) r[j] = fence(e[j] * e[j]);
#pragma unroll
    for (int t = 1; t < 8; ++t)
#pragma unroll
        for (int j = 0; j < 8; ++j) r[j] = r[j] + fence(e[8 * t + j] * e[8 * t + j]);
    return ((r[0] + r[1]) + (r[2] + r[3])) + ((r[4] + r[5]) + (r[6] + r[7]));
}

// Bit-exact reference score: s = fl( fl(R+N) - 2*dot ), dot = ascending-i
// sequential FMA chain (validated absmax=0 in R2..R19).
static __device__ __forceinline__ float exact_score(
    const float* __restrict__ xrow, const float* __restrict__ erow, float R,
    float N) {
    float a = 0.0f;
#pragma unroll
    for (int i = 0; i < D; ++i) a = __builtin_fmaf(xrow[i], erow[i], a);
    return (R + N) - 2.0f * a;
}

// ---------------- Kernel 1: embedding prep (bf16 + norms) ----------------
__global__ void prep_emb_kernel(const float* __restrict__ emb,
                                float* __restrict__ enorm,
                                unsigned short* __restrict__ e_hi,
                                float* __restrict__ loss_slot) {
    int k = blockIdx.x * blockDim.x + threadIdx.x;
    if (k == 0) *loss_slot = 0.0f;
    if (k >= K) return;
    enorm[k] = np_sumsq64(emb + k * D);
    const float* e = emb + k * D;
#pragma unroll
    for (int i = 0; i < D; ++i) e_hi[k * D + i] = f2bf(e[i]);
}

// ---------------- Kernel 2: 2-pass MFMA argmin, DEFERRED-CONSUME pipeline ---
// EXACT R16 algorithm/layout (109.9us, absmax=0). One change: accumulator
// consumption (fminf / threshold-check) for tile nt executes during tile
// nt+1's MFMA pipe time (acc quads double-buffered by parity, init -inf ->
// t=+inf no-op; drained after the loop). Rationale: R16's residual is the
// MFMA->VALU acc-read hazard (~25cyc x 4 chains x 32 tiles/wave); R18 showed
// load-depth doesn't matter, R19 showed occupancy doesn't either. Per-elem
// work stays fmaf+fminf (R10/13/16 fast pattern) -- only placement moves.
__global__ __launch_bounds__(256, 1) void argmin_kernel(
    const float* __restrict__ x, const float* __restrict__ emb,
    const float* __restrict__ enorm, const unsigned short* __restrict__ e_hi,
    float* __restrict__ out_q, float* __restrict__ idx_f,
    float* __restrict__ loss_slot) {
    const int l = threadIdx.x & 63;
    const int w = threadIdx.x >> 6;
    const int rowbase = blockIdx.x * 64;
    const int cbase = w * 256;

    __shared__ float wminA[4][64];
    __shared__ float gmin[64];
    __shared__ int cnt[64];
    __shared__ int clist[64][8];
    __shared__ int bidx[64];
    __shared__ float wsum[4];

    // ---- A-fragments: bf16(x), named SSA short8v. Layout (16x16x32):
    // row = l&15, k = h*32 + (l>>4)*8 + i; B uses the same permutation.
#define DECL_A(rt, h)                                                       \
    short8v Ahi_##rt##_##h;                                                 \
    { const float* p = x + (size_t)(rowbase + rt * 16 + (l & 15)) * D +     \
                       h * 32 + (l >> 4) * 8;                               \
      float4 q0 = *(const float4*)p, q1 = *(const float4*)(p + 4);          \
      Ahi_##rt##_##h[0] = (short)f2bf(q0.x);                                \
      Ahi_##rt##_##h[1] = (short)f2bf(q0.y);                                \
      Ahi_##rt##_##h[2] = (short)f2bf(q0.z);                                \
      Ahi_##rt##_##h[3] = (short)f2bf(q0.w);                                \
      Ahi_##rt##_##h[4] = (short)f2bf(q1.x);                                \
      Ahi_##rt##_##h[5] = (short)f2bf(q1.y);                                \
      Ahi_##rt##_##h[6] = (short)f2bf(q1.z);                                \
      Ahi_##rt##_##h[7] = (short)f2bf(q1.w); }
    DECL_A(0, 0) DECL_A(0, 1) DECL_A(1, 0) DECL_A(1, 1)
    DECL_A(2, 0) DECL_A(2, 1) DECL_A(3, 0) DECL_A(3, 1)

    const int koff = (l >> 4) * 8;
    const unsigned short* __restrict__ bh =
        e_hi + (size_t)(cbase + (l & 15)) * D + koff;
    const float* __restrict__ bn = enorm + cbase + (l & 15);

#define LOADT(H0, H1, NN, off)                                              \
    H0 = *(const short8v*)(bh + (size_t)(off) * 1024);                      \
    H1 = *(const short8v*)(bh + (size_t)(off) * 1024 + 32);                 \
    NN = bn[(off) * 16];

    // slot s = rt*4 + r maps to row (s/4)*16 + (l>>4)*4 + (s%4)
#define SLOTROW(s) (((s) / 4) * 16 + (l >> 4) * 4 + ((s) % 4))

    const f32x4 zero4 = {0.f, 0.f, 0.f, 0.f};
    const float NINF = -__builtin_inff();
    const f32x4 ninf4 = {NINF, NINF, NINF, NINF};

    // parity acc quads (deferred consumption state)
    f32x4 aP_0, aP_1, aP_2, aP_3, aQ_0, aQ_1, aQ_2, aQ_3;

#define TCOMP(X, BH0, BH1)                                                  \
    a##X##_0 = __builtin_amdgcn_mfma_f32_16x16x32_bf16(Ahi_0_0, BH0, zero4, 0, 0, 0); \
    a##X##_0 = __builtin_amdgcn_mfma_f32_16x16x32_bf16(Ahi_0_1, BH1, a##X##_0, 0, 0, 0); \
    a##X##_1 = __builtin_amdgcn_mfma_f32_16x16x32_bf16(Ahi_1_0, BH0, zero4, 0, 0, 0); \
    a##X##_1 = __builtin_amdgcn_mfma_f32_16x16x32_bf16(Ahi_1_1, BH1, a##X##_1, 0, 0, 0); \
    a##X##_2 = __builtin_amdgcn_mfma_f32_16x16x32_bf16(Ahi_2_0, BH0, zero4, 0, 0, 0); \
    a##X##_2 = __builtin_amdgcn_mfma_f32_16x16x32_bf16(Ahi_2_1, BH1, a##X##_2, 0, 0, 0); \
    a##X##_3 = __builtin_amdgcn_mfma_f32_16x16x32_bf16(Ahi_3_0, BH0, zero4, 0, 0, 0); \
    a##X##_3 = __builtin_amdgcn_mfma_f32_16x16x32_bf16(Ahi_3_1, BH1, a##X##_3, 0, 0, 0);

    // =================== PASS A: fminf min, deferred consume ================
#define DECL_MA(s) float mA_##s = 3.402823466e+38f;
    FORSLOT(DECL_MA)
#define UPA(s, av, NN) mA_##s = fminf(mA_##s, __builtin_fmaf(-2.0f, (av), NN));
#define TCONSA(X, NN)                                                       \
    UPA(0, a##X##_0[0], NN) UPA(1, a##X##_0[1], NN)                         \
    UPA(2, a##X##_0[2], NN) UPA(3, a##X##_0[3], NN)                         \
    UPA(4, a##X##_1[0], NN) UPA(5, a##X##_1[1], NN)                         \
    UPA(6, a##X##_1[2], NN) UPA(7, a##X##_1[3], NN)                         \
    UPA(8, a##X##_2[0], NN) UPA(9, a##X##_2[1], NN)                         \
    UPA(10, a##X##_2[2], NN) UPA(11, a##X##_2[3], NN)                       \
    UPA(12, a##X##_3[0], NN) UPA(13, a##X##_3[1], NN)                       \
    UPA(14, a##X##_3[2], NN) UPA(15, a##X##_3[3], NN)
    {
        short8v pH0, pH1, qH0, qH1;
        float pN, qN, dNp = 0.f, dNq = 0.f;
        aQ_0 = ninf4; aQ_1 = ninf4; aQ_2 = ninf4; aQ_3 = ninf4;
        LOADT(pH0, pH1, pN, 0)
        for (int nt = 0; nt < 16; nt += 2) {
            LOADT(qH0, qH1, qN, nt + 1)
            TCOMP(P, pH0, pH1)          // tile nt
            dNp = pN;
            TCONSA(Q, dNq)              // consume tile nt-1
            const int nxt = (nt + 2 < 16) ? nt + 2 : 15;
            LOADT(pH0, pH1, pN, nxt)
            TCOMP(Q, qH0, qH1)          // tile nt+1
            dNq = qN;
            TCONSA(P, dNp)              // consume tile nt
        }
        TCONSA(Q, dNq)                  // drain tile 15
    }
    // C/D layout: col = l&15 (code), row-group = 16 contiguous lanes.
#define BFA(s)                                                              \
    mA_##s = fminf(mA_##s, __shfl_xor(mA_##s, 1));                          \
    mA_##s = fminf(mA_##s, __shfl_xor(mA_##s, 2));                          \
    mA_##s = fminf(mA_##s, __shfl_xor(mA_##s, 4));                          \
    mA_##s = fminf(mA_##s, __shfl_xor(mA_##s, 8));
    FORSLOT(BFA)
#define WRA(s) if ((l & 15) == 0) wminA[w][SLOTROW(s)] = mA_##s;
    FORSLOT(WRA)
    __syncthreads();
    if (threadIdx.x < 64) {
        gmin[threadIdx.x] =
            fminf(fminf(wminA[0][threadIdx.x], wminA[1][threadIdx.x]),
                  fminf(wminA[2][threadIdx.x], wminA[3][threadIdx.x]));
        cnt[threadIdx.x] = 0;
    }
    __syncthreads();

    // =================== PASS B: candidate collect, deferred consume ========
#define DECL_T(s) const float thr_##s = gmin[SLOTROW(s)] + DELTA;
    FORSLOT(DECL_T)
#define CHKD(s, av, NN, CC)                                                 \
    { float t = __builtin_fmaf(-2.0f, (av), NN);                            \
      if (t <= thr_##s) {                                                   \
          int row = SLOTROW(s);                                             \
          int pos = atomicAdd(&cnt[row], 1);                                \
          if (pos < 8) clist[row][pos] = CC; } }
#define TCONSB(X, NN, CC)                                                   \
    CHKD(0, a##X##_0[0], NN, CC) CHKD(1, a##X##_0[1], NN, CC)               \
    CHKD(2, a##X##_0[2], NN, CC) CHKD(3, a##X##_0[3], NN, CC)               \
    CHKD(4, a##X##_1[0], NN, CC) CHKD(5, a##X##_1[1], NN, CC)               \
    CHKD(6, a##X##_1[2], NN, CC) CHKD(7, a##X##_1[3], NN, CC)               \
    CHKD(8, a##X##_2[0], NN, CC) CHKD(9, a##X##_2[1], NN, CC)               \
    CHKD(10, a##X##_2[2], NN, CC) CHKD(11, a##X##_2[3], NN, CC)             \
    CHKD(12, a##X##_3[0], NN, CC) CHKD(13, a##X##_3[1], NN, CC)             \
    CHKD(14, a##X##_3[2], NN, CC) CHKD(15, a##X##_3[3], NN, CC)
    {
        short8v pH0, pH1, qH0, qH1;
        float pN, qN, dNp = 0.f, dNq = 0.f;
        int dCp = 0, dCq = 0;
        aQ_0 = ninf4; aQ_1 = ninf4; aQ_2 = ninf4; aQ_3 = ninf4;
        LOADT(pH0, pH1, pN, 0)
        for (int nt = 0; nt < 16; nt += 2) {
            LOADT(qH0, qH1, qN, nt + 1)
            TCOMP(P, pH0, pH1)
            dNp = pN;
            int cP = cbase + (l & 15) + nt * 16;
            TCONSB(Q, dNq, dCq)
            dCp = cP;
            const int nxt = (nt + 2 < 16) ? nt + 2 : 15;
            LOADT(pH0, pH1, pN, nxt)
            TCOMP(Q, qH0, qH1)
            dNq = qN;
            int cQ = cbase + (l & 15) + (nt + 1) * 16;
            TCONSB(P, dNp, dCp)
            dCq = cQ;
        }
        TCONSB(Q, dNq, dCq)
    }
    __syncthreads();

    // ---- select / rescue (1 thread per row), bit-exact final answer ----
    if (threadIdx.x < 64) {
        const int row = threadIdx.x;
        const int n = cnt[row];
        int bk;
        if (n == 1) {
            bk = clist[row][0];
        } else {
            const float* xrow = x + (size_t)(rowbase + row) * D;
            const float R = np_sumsq64(xrow);
            float sb = 3.402823466e+38f;
            int kb = 0x7fffffff;
            if (n <= 8) {
                for (int i = 0; i < n; ++i) {
                    int c = clist[row][i];
                    float s = exact_score(xrow, emb + ((size_t)c << 6), R,
                                          enorm[c]);
                    if (s < sb || (s == sb && c < kb)) { sb = s; kb = c; }
                }
            } else {  // clist overflow: full exact scan (essentially never)
                for (int c = 0; c < K; ++c) {
                    float s = exact_score(xrow, emb + ((size_t)c << 6), R,
                                          enorm[c]);
                    if (s < sb || (s == sb && c < kb)) { sb = s; kb = c; }
                }
            }
            bk = kb;
        }
        bidx[row] = bk;
        idx_f[rowbase + row] = (float)bk;
    }
    __syncthreads();

    // ---- fused epilogue: gather + straight-through + loss ----
    {
        const int row = threadIdx.x >> 2;
        const int d0 = (threadIdx.x & 3) * 16;
        const int bk = bidx[row];
        const float4* xq = (const float4*)(x + (size_t)(rowbase + row) * D + d0);
        const float4* eq = (const float4*)(emb + ((size_t)bk << 6) + d0);
        float4* oq = (float4*)(out_q + (size_t)(rowbase + row) * D + d0);
        float lsum = 0.f;
#pragma unroll
        for (int i = 0; i < 4; ++i) {
            float4 xv = xq[i];
            float4 ev = eq[i];
            float dx = ev.x - xv.x, dy = ev.y - xv.y, dz = ev.z - xv.z,
                  dw = ev.w - xv.w;
            float4 o;
            o.x = xv.x + dx;
            o.y = xv.y + dy;
            o.z = xv.z + dz;
            o.w = xv.w + dw;
            oq[i] = o;
            lsum = __builtin_fmaf(dx, dx, lsum);
            lsum = __builtin_fmaf(dy, dy, lsum);
            lsum = __builtin_fmaf(dz, dz, lsum);
            lsum = __builtin_fmaf(dw, dw, lsum);
        }
#pragma unroll
        for (int o = 32; o > 0; o >>= 1) lsum += __shfl_xor(lsum, o);
        if (l == 0) wsum[w] = lsum;
        __syncthreads();
        if (threadIdx.x == 0)
            atomicAdd(loss_slot, ((wsum[0] + wsum[1]) + (wsum[2] + wsum[3])) *
                                     ((1.0f + COMMIT) / (float)NELEM));
    }
}

extern "C" void kernel_launch(void* const* d_in, const int* in_sizes, int n_in,
                              void* d_out, int out_size, void* d_ws,
                              size_t ws_size, hipStream_t stream) {
    const float* x = (const float*)d_in[0];    // [32,4096,64] f32
    const float* emb = (const float*)d_in[1];  // [1024,64] f32

    float* out = (float*)d_out;
    float* loss_slot = out;              // out[0]
    float* out_q = out + 1;              // out[1 .. 1+NELEM)
    float* idx_f = out + 1 + NELEM;      // indices as f32

    // workspace layout (16B-aligned slabs)
    float* enorm = (float*)d_ws;                                    // 4 KB
    unsigned short* e_hi = (unsigned short*)((char*)d_ws + 4096);   // 128 KB

    prep_emb_kernel<<<(K + 255) / 256, 256, 0, stream>>>(emb, enorm, e_hi,
                                                         loss_slot);
    argmin_kernel<<<NROWS / 64, 256, 0, stream>>>(x, emb, enorm, e_hi, out_q,
                                                  idx_f, loss_slot);
}

// Round 21
// 110.650 us; speedup vs baseline: 1.5127x; 1.0762x over previous
//
#include <hip/hip_runtime.h>

#define D 64
#define K 1024
#define NROWS (32 * 4096)
#define NELEM (NROWS * D)
#define COMMIT 0.25f
#define DELTA 1.2e-4f
#define HDELTA 6e-5f   // DELTA/2 in acc-space (t = -2*acc)

typedef __attribute__((ext_vector_type(8))) short short8v;   // 8 bf16
typedef __attribute__((ext_vector_type(4))) float f32x4;
typedef unsigned long long u64;

#define FORSLOT(M) M(0) M(1) M(2) M(3) M(4) M(5) M(6) M(7) \
                   M(8) M(9) M(10) M(11) M(12) M(13) M(14) M(15)

static __device__ __forceinline__ float fence(float v) {
    asm("" : "+v"(v));
    return v;
}

// f32 -> bf16 bits, round-to-nearest-even (finite inputs only).
static __device__ __forceinline__ unsigned short f2bf(float f) {
    unsigned u = __float_as_uint(f);
    return (unsigned short)((u + 0x7FFFu + ((u >> 16) & 1u)) >> 16);
}

// numpy pairwise_sum for n=64: 8 accumulators stride 8, then pairwise tree.
static __device__ __forceinline__ float np_sumsq64(const float* __restrict__ e) {
    float r[8];
#pragma unroll
    for (int j = 0; j < 8; ++j) r[j] = fence(e[j] * e[j]);
#pragma unroll
    for (int t = 1; t < 8; ++t)
#pragma unroll
        for (int j = 0; j < 8; ++j) r[j] = r[j] + fence(e[8 * t + j] * e[8 * t + j]);
    return ((r[0] + r[1]) + (r[2] + r[3])) + ((r[4] + r[5]) + (r[6] + r[7]));
}

// Bit-exact reference score: s = fl( fl(R+N) - 2*dot ), dot = ascending-i
// sequential FMA chain (validated absmax=0 in R2..R20).
static __device__ __forceinline__ float exact_score(
    const float* __restrict__ xrow, const float* __restrict__ erow, float R,
    float N) {
    float a = 0.0f;
#pragma unroll
    for (int i = 0; i < D; ++i) a = __builtin_fmaf(xrow[i], erow[i], a);
    return (R + N) - 2.0f * a;
}

// ---------------- Kernel 1: embedding prep (bf16 + norms + -N/2) -----------
__global__ void prep_emb_kernel(const float* __restrict__ emb,
                                float* __restrict__ enorm,
                                float* __restrict__ enorm_nh,
                                unsigned short* __restrict__ e_hi,
                                float* __restrict__ loss_slot) {
    int k = blockIdx.x * blockDim.x + threadIdx.x;
    if (k == 0) *loss_slot = 0.0f;
    if (k >= K) return;
    float n = np_sumsq64(emb + k * D);
    enorm[k] = n;
    enorm_nh[k] = -0.5f * n;   // exact scaling
    const float* e = emb + k * D;
#pragma unroll
    for (int i = 0; i < D; ++i) e_hi[k * D + i] = f2bf(e[i]);
}

// ---------------- Kernel 2: 2-pass MFMA argmin, Nc-folded-into-acc ---------
// R16 structure (109.9us, absmax=0) with the consume VALU halved: acc is
// initialized to splat(-N_k/2) (legal: C/D layout gives each lane ONE code
// column, so all 4 quad elements share N_k). After the K-chain acc =
// dot - N_k/2, and argmin t=-2*acc == argmax acc. Pass A consume = 1 fmaxf
// per element (was fmaf+fminf); pass B = 1 compare (acc >= gmax - DELTA/2).
// Same 18-sigma inclusion margin; exact-chain rescue unchanged -> absmax 0
// is structural. R16's 32 VALU/tile consume was ~45% of hot-loop instrs and
// VALUBusy (30% ~= 32us) the largest pipe term (R18/R19/R20 falsified load
// depth / occupancy / acc-hazard).
__global__ __launch_bounds__(256, 1) void argmin_kernel(
    const float* __restrict__ x, const float* __restrict__ emb,
    const float* __restrict__ enorm, const float* __restrict__ enorm_nh,
    const unsigned short* __restrict__ e_hi, float* __restrict__ out_q,
    float* __restrict__ idx_f, float* __restrict__ loss_slot) {
    const int l = threadIdx.x & 63;
    const int w = threadIdx.x >> 6;
    const int rowbase = blockIdx.x * 64;
    const int cbase = w * 256;

    __shared__ float wmaxA[4][64];
    __shared__ float gmax[64];
    __shared__ int cnt[64];
    __shared__ int clist[64][8];
    __shared__ int bidx[64];
    __shared__ float wsum[4];

    // ---- A-fragments: bf16(x), named SSA short8v. Layout (16x16x32):
    // row = l&15, k = h*32 + (l>>4)*8 + i; B uses the same permutation.
#define DECL_A(rt, h)                                                       \
    short8v Ahi_##rt##_##h;                                                 \
    { const float* p = x + (size_t)(rowbase + rt * 16 + (l & 15)) * D +     \
                       h * 32 + (l >> 4) * 8;                               \
      float4 q0 = *(const float4*)p, q1 = *(const float4*)(p + 4);          \
      Ahi_##rt##_##h[0] = (short)f2bf(q0.x);                                \
      Ahi_##rt##_##h[1] = (short)f2bf(q0.y);                                \
      Ahi_##rt##_##h[2] = (short)f2bf(q0.z);                                \
      Ahi_##rt##_##h[3] = (short)f2bf(q0.w);                                \
      Ahi_##rt##_##h[4] = (short)f2bf(q1.x);                                \
      Ahi_##rt##_##h[5] = (short)f2bf(q1.y);                                \
      Ahi_##rt##_##h[6] = (short)f2bf(q1.z);                                \
      Ahi_##rt##_##h[7] = (short)f2bf(q1.w); }
    DECL_A(0, 0) DECL_A(0, 1) DECL_A(1, 0) DECL_A(1, 1)
    DECL_A(2, 0) DECL_A(2, 1) DECL_A(3, 0) DECL_A(3, 1)

    const int koff = (l >> 4) * 8;
    const unsigned short* __restrict__ bh =
        e_hi + (size_t)(cbase + (l & 15)) * D + koff;
    const float* __restrict__ bn = enorm_nh + cbase + (l & 15);

#define LOADT(H0, H1, NN, off)                                              \
    H0 = *(const short8v*)(bh + (size_t)(off) * 1024);                      \
    H1 = *(const short8v*)(bh + (size_t)(off) * 1024 + 32);                 \
    NN = bn[(off) * 16];

    // slot s = rt*4 + r maps to row (s/4)*16 + (l>>4)*4 + (s%4)
#define SLOTROW(s) (((s) / 4) * 16 + (l >> 4) * 4 + ((s) % 4))

    // =================== PASS A: fmaxf max, ping-pong ===================
#define DECL_MA(s) float mA_##s = -3.402823466e+38f;
    FORSLOT(DECL_MA)
#define MFMA2A(rt, sA, sB, sC, sD)                                          \
    { f32x4 acc = {Nc, Nc, Nc, Nc};                                         \
      acc = __builtin_amdgcn_mfma_f32_16x16x32_bf16(Ahi_##rt##_0, Bhi0, acc, 0, 0, 0); \
      acc = __builtin_amdgcn_mfma_f32_16x16x32_bf16(Ahi_##rt##_1, Bhi1, acc, 0, 0, 0); \
      mA_##sA = fmaxf(mA_##sA, acc[0]);                                     \
      mA_##sB = fmaxf(mA_##sB, acc[1]);                                     \
      mA_##sC = fmaxf(mA_##sC, acc[2]);                                     \
      mA_##sD = fmaxf(mA_##sD, acc[3]); }
#define TILEA(H0, H1, NN)                                                   \
    { const short8v Bhi0 = H0, Bhi1 = H1;                                   \
      const float Nc = NN;                                                  \
      MFMA2A(0, 0, 1, 2, 3) MFMA2A(1, 4, 5, 6, 7)                           \
      MFMA2A(2, 8, 9, 10, 11) MFMA2A(3, 12, 13, 14, 15) }
    {
        short8v pH0, pH1, qH0, qH1;
        float pN, qN;
        LOADT(pH0, pH1, pN, 0)
        for (int nt = 0; nt < 16; nt += 2) {
            LOADT(qH0, qH1, qN, nt + 1)
            TILEA(pH0, pH1, pN)
            const int nxt = (nt + 2 < 16) ? nt + 2 : 15;
            LOADT(pH0, pH1, pN, nxt)
            TILEA(qH0, qH1, qN)
        }
    }
    // C/D layout: col = l&15 (code), row-group = 16 contiguous lanes.
#define BFA(s)                                                              \
    mA_##s = fmaxf(mA_##s, __shfl_xor(mA_##s, 1));                          \
    mA_##s = fmaxf(mA_##s, __shfl_xor(mA_##s, 2));                          \
    mA_##s = fmaxf(mA_##s, __shfl_xor(mA_##s, 4));                          \
    mA_##s = fmaxf(mA_##s, __shfl_xor(mA_##s, 8));
    FORSLOT(BFA)
#define WRA(s) if ((l & 15) == 0) wmaxA[w][SLOTROW(s)] = mA_##s;
    FORSLOT(WRA)
    __syncthreads();
    if (threadIdx.x < 64) {
        gmax[threadIdx.x] =
            fmaxf(fmaxf(wmaxA[0][threadIdx.x], wmaxA[1][threadIdx.x]),
                  fmaxf(wmaxA[2][threadIdx.x], wmaxA[3][threadIdx.x]));
        cnt[threadIdx.x] = 0;
    }
    __syncthreads();

    // =================== PASS B: candidate collection ===================
#define DECL_T(s) const float thr_##s = gmax[SLOTROW(s)] - HDELTA;
    FORSLOT(DECL_T)
#define CHK(s, av)                                                          \
    { if ((av) >= thr_##s) {                                                \
          int row = SLOTROW(s);                                             \
          int pos = atomicAdd(&cnt[row], 1);                                \
          if (pos < 8) clist[row][pos] = code;                              \
      } }
#define MFMA2B(rt, sA, sB, sC, sD)                                          \
    { f32x4 acc = {Nc, Nc, Nc, Nc};                                         \
      acc = __builtin_amdgcn_mfma_f32_16x16x32_bf16(Ahi_##rt##_0, Bhi0, acc, 0, 0, 0); \
      acc = __builtin_amdgcn_mfma_f32_16x16x32_bf16(Ahi_##rt##_1, Bhi1, acc, 0, 0, 0); \
      CHK(sA, acc[0]) CHK(sB, acc[1]) CHK(sC, acc[2]) CHK(sD, acc[3]) }
#define TILEB(H0, H1, NN, NT)                                               \
    { const short8v Bhi0 = H0, Bhi1 = H1;                                   \
      const float Nc = NN;                                                  \
      const int code = cbase + (l & 15) + (NT) * 16;                        \
      MFMA2B(0, 0, 1, 2, 3) MFMA2B(1, 4, 5, 6, 7)                           \
      MFMA2B(2, 8, 9, 10, 11) MFMA2B(3, 12, 13, 14, 15) }
    {
        short8v pH0, pH1, qH0, qH1;
        float pN, qN;
        LOADT(pH0, pH1, pN, 0)
        for (int nt = 0; nt < 16; nt += 2) {
            LOADT(qH0, qH1, qN, nt + 1)
            TILEB(pH0, pH1, pN, nt)
            const int nxt = (nt + 2 < 16) ? nt + 2 : 15;
            LOADT(pH0, pH1, pN, nxt)
            TILEB(qH0, qH1, qN, nt + 1)
        }
    }
    __syncthreads();

    // ---- select / rescue (1 thread per row), bit-exact final answer ----
    if (threadIdx.x < 64) {
        const int row = threadIdx.x;
        const int n = cnt[row];
        int bk;
        if (n == 1) {
            bk = clist[row][0];
        } else {
            const float* xrow = x + (size_t)(rowbase + row) * D;
            const float R = np_sumsq64(xrow);
            float sb = 3.402823466e+38f;
            int kb = 0x7fffffff;
            if (n <= 8) {
                for (int i = 0; i < n; ++i) {
                    int c = clist[row][i];
                    float s = exact_score(xrow, emb + ((size_t)c << 6), R,
                                          enorm[c]);
                    if (s < sb || (s == sb && c < kb)) { sb = s; kb = c; }
                }
            } else {  // clist overflow: full exact scan (essentially never)
                for (int c = 0; c < K; ++c) {
                    float s = exact_score(xrow, emb + ((size_t)c << 6), R,
                                          enorm[c]);
                    if (s < sb || (s == sb && c < kb)) { sb = s; kb = c; }
                }
            }
            bk = kb;
        }
        bidx[row] = bk;
        idx_f[rowbase + row] = (float)bk;
    }
    __syncthreads();

    // ---- fused epilogue: gather + straight-through + loss ----
    {
        const int row = threadIdx.x >> 2;
        const int d0 = (threadIdx.x & 3) * 16;
        const int bk = bidx[row];
        const float4* xq = (const float4*)(x + (size_t)(rowbase + row) * D + d0);
        const float4* eq = (const float4*)(emb + ((size_t)bk << 6) + d0);
        float4* oq = (float4*)(out_q + (size_t)(rowbase + row) * D + d0);
        float lsum = 0.f;
#pragma unroll
        for (int i = 0; i < 4; ++i) {
            float4 xv = xq[i];
            float4 ev = eq[i];
            float dx = ev.x - xv.x, dy = ev.y - xv.y, dz = ev.z - xv.z,
                  dw = ev.w - xv.w;
            float4 o;
            o.x = xv.x + dx;
            o.y = xv.y + dy;
            o.z = xv.z + dz;
            o.w = xv.w + dw;
            oq[i] = o;
            lsum = __builtin_fmaf(dx, dx, lsum);
            lsum = __builtin_fmaf(dy, dy, lsum);
            lsum = __builtin_fmaf(dz, dz, lsum);
            lsum = __builtin_fmaf(dw, dw, lsum);
        }
#pragma unroll
        for (int o = 32; o > 0; o >>= 1) lsum += __shfl_xor(lsum, o);
        if (l == 0) wsum[w] = lsum;
        __syncthreads();
        if (threadIdx.x == 0)
            atomicAdd(loss_slot, ((wsum[0] + wsum[1]) + (wsum[2] + wsum[3])) *
                                     ((1.0f + COMMIT) / (float)NELEM));
    }
}

extern "C" void kernel_launch(void* const* d_in, const int* in_sizes, int n_in,
                              void* d_out, int out_size, void* d_ws,
                              size_t ws_size, hipStream_t stream) {
    const float* x = (const float*)d_in[0];    // [32,4096,64] f32
    const float* emb = (const float*)d_in[1];  // [1024,64] f32

    float* out = (float*)d_out;
    float* loss_slot = out;              // out[0]
    float* out_q = out + 1;              // out[1 .. 1+NELEM)
    float* idx_f = out + 1 + NELEM;      // indices as f32

    // workspace layout (16B-aligned slabs)
    float* enorm = (float*)d_ws;                                    // 4 KB
    float* enorm_nh = (float*)((char*)d_ws + 4096);                 // 4 KB
    unsigned short* e_hi = (unsigned short*)((char*)d_ws + 8192);   // 128 KB

    prep_emb_kernel<<<(K + 255) / 256, 256, 0, stream>>>(emb, enorm, enorm_nh,
                                                         e_hi, loss_slot);
    argmin_kernel<<<NROWS / 64, 256, 0, stream>>>(x, emb, enorm, enorm_nh,
                                                  e_hi, out_q, idx_f,
                                                  loss_slot);
}

// Round 22
// 98.611 us; speedup vs baseline: 1.6974x; 1.1221x over previous
//
#include <hip/hip_runtime.h>

#define D 64
#define K 1024
#define NROWS (32 * 4096)
#define NELEM (NROWS * D)
#define COMMIT 0.25f
#define DELTA 1.2e-4f
#define HDELTA 6e-5f   // DELTA/2 in acc-space (t = -2*acc)
#define RPB 128        // rows per block (32 per wave)
#define CHUNK 256      // codes staged per LDS chunk
#define EPAD 68        // padded code-row stride in ushorts (136B): 2-way banks

typedef __attribute__((ext_vector_type(8))) short short8v;   // 8 bf16
typedef __attribute__((ext_vector_type(4))) float f32x4;
typedef unsigned long long u64;

#define FORSLOT8(M) M(0) M(1) M(2) M(3) M(4) M(5) M(6) M(7)

static __device__ __forceinline__ float fence(float v) {
    asm("" : "+v"(v));
    return v;
}

// f32 -> bf16 bits, round-to-nearest-even (finite inputs only).
static __device__ __forceinline__ unsigned short f2bf(float f) {
    unsigned u = __float_as_uint(f);
    return (unsigned short)((u + 0x7FFFu + ((u >> 16) & 1u)) >> 16);
}

// numpy pairwise_sum for n=64: 8 accumulators stride 8, then pairwise tree.
static __device__ __forceinline__ float np_sumsq64(const float* __restrict__ e) {
    float r[8];
#pragma unroll
    for (int j = 0; j < 8; ++j) r[j] = fence(e[j] * e[j]);
#pragma unroll
    for (int t = 1; t < 8; ++t)
#pragma unroll
        for (int j = 0; j < 8; ++j) r[j] = r[j] + fence(e[8 * t + j] * e[8 * t + j]);
    return ((r[0] + r[1]) + (r[2] + r[3])) + ((r[4] + r[5]) + (r[6] + r[7]));
}

// Bit-exact reference score: s = fl( fl(R+N) - 2*dot ), dot = ascending-i
// sequential FMA chain (validated absmax=0 in R2..R21).
static __device__ __forceinline__ float exact_score(
    const float* __restrict__ xrow, const float* __restrict__ erow, float R,
    float N) {
    float a = 0.0f;
#pragma unroll
    for (int i = 0; i < D; ++i) a = __builtin_fmaf(xrow[i], erow[i], a);
    return (R + N) - 2.0f * a;
}

// ---------------- Kernel 1: embedding prep (bf16 + norms + -N/2) -----------
__global__ void prep_emb_kernel(const float* __restrict__ emb,
                                float* __restrict__ enorm,
                                float* __restrict__ enorm_nh,
                                unsigned short* __restrict__ e_hi,
                                float* __restrict__ loss_slot) {
    int k = blockIdx.x * blockDim.x + threadIdx.x;
    if (k == 0) *loss_slot = 0.0f;
    if (k >= K) return;
    float n = np_sumsq64(emb + k * D);
    enorm[k] = n;
    enorm_nh[k] = -0.5f * n;   // exact scaling
    const float* e = emb + k * D;
#pragma unroll
    for (int i = 0; i < D; ++i) e_hi[k * D + i] = f2bf(e[i]);
}

// ---------------- Kernel 2: LDS-shared-B 2-pass MFMA argmin -----------------
// R21's validated math (Nc-folded acc, fmaxf consume, candidates + bit-exact
// rescue) restructured so the hot loop issues ZERO global loads: waves share
// CODES (staged in LDS, 4 chunks of 256) and split ROWS (32/wave). Rationale:
// R18-R21 falsified load-depth/occupancy/acc-hazard/VALU-count; per-tile
// scaling (R16 vs R19: ~900cyc/tile, pipes idle) indicts the VMEM issue path
// (L1 thrash + TA/MSHR backpressure from 33-line gathers) -- a regime where
// none of those levers act. LDS B: 136B-padded rows -> 2-way conflicts
// (free, m136); coalesced 16B/lane staging; rows wave-private so gmax stays
// in registers (no cross-wave merge). LDS ~39KB -> 4 blocks/CU.
__global__ __launch_bounds__(256, 1) void argmin_kernel(
    const float* __restrict__ x, const float* __restrict__ emb,
    const float* __restrict__ enorm, const float* __restrict__ enorm_nh,
    const unsigned short* __restrict__ e_hi, float* __restrict__ out_q,
    float* __restrict__ idx_f, float* __restrict__ loss_slot) {
    const int tid = threadIdx.x;
    const int l = tid & 63;
    const int w = tid >> 6;
    const int col = l & 15;
    const int koff = (l >> 4) * 8;                 // elements
    const int blockrow = blockIdx.x * RPB;
    const int wrow = blockrow + w * 32;            // wave-private 32 rows

    __shared__ unsigned short eB[CHUNK * EPAD];    // 34,816 B
    __shared__ float nB[CHUNK];                    // 1 KB (-N/2)
    __shared__ int cnt[RPB];
    __shared__ int clist[RPB][4];
    __shared__ int bidx[RPB];
    __shared__ float wsum[4];

    // ---- A-fragments: bf16(x), named SSA. Layout (16x16x32): row = col,
    // k = h*32 + koff + i; B uses the same per-lane permutation (validated).
#define DECL_A(rt, h)                                                       \
    short8v Ahi_##rt##_##h;                                                 \
    { const float* p = x + (size_t)(wrow + rt * 16 + col) * D + h * 32 + koff; \
      float4 q0 = *(const float4*)p, q1 = *(const float4*)(p + 4);          \
      Ahi_##rt##_##h[0] = (short)f2bf(q0.x);                                \
      Ahi_##rt##_##h[1] = (short)f2bf(q0.y);                                \
      Ahi_##rt##_##h[2] = (short)f2bf(q0.z);                                \
      Ahi_##rt##_##h[3] = (short)f2bf(q0.w);                                \
      Ahi_##rt##_##h[4] = (short)f2bf(q1.x);                                \
      Ahi_##rt##_##h[5] = (short)f2bf(q1.y);                                \
      Ahi_##rt##_##h[6] = (short)f2bf(q1.z);                                \
      Ahi_##rt##_##h[7] = (short)f2bf(q1.w); }
    DECL_A(0, 0) DECL_A(0, 1) DECL_A(1, 0) DECL_A(1, 1)

    // slot s = rt*4 + r -> row-within-wave (s/4)*16 + (l>>4)*4 + (s%4)
#define SLOTROW(s) (((s) / 4) * 16 + (l >> 4) * 4 + ((s) % 4))

#define STAGE(c)                                                            \
    {                                                                       \
        _Pragma("unroll")                                                   \
        for (int i = 0; i < 8; ++i) {                                       \
            int G = tid + i * 256;        /* 16B granule id, 0..2047 */     \
            int cd = G >> 3, wi = G & 7;                                    \
            *(short8v*)(&eB[cd * EPAD + wi * 8]) =                          \
                *(const short8v*)(e_hi +                                    \
                    (((size_t)((c) * CHUNK + cd)) << 6) + wi * 8);          \
        }                                                                   \
        nB[tid] = enorm_nh[(c) * CHUNK + tid];                              \
    }

    // =================== PASS A: fmaxf max over 4 staged chunks =============
#define DECL_MA(s) float mA_##s = -3.402823466e+38f;
    FORSLOT8(DECL_MA)
#define MFMA2A(rt, sA, sB, sC, sD)                                          \
    { f32x4 acc = {Nc, Nc, Nc, Nc};                                         \
      acc = __builtin_amdgcn_mfma_f32_16x16x32_bf16(Ahi_##rt##_0, Bhi0, acc, 0, 0, 0); \
      acc = __builtin_amdgcn_mfma_f32_16x16x32_bf16(Ahi_##rt##_1, Bhi1, acc, 0, 0, 0); \
      mA_##sA = fmaxf(mA_##sA, acc[0]);                                     \
      mA_##sB = fmaxf(mA_##sB, acc[1]);                                     \
      mA_##sC = fmaxf(mA_##sC, acc[2]);                                     \
      mA_##sD = fmaxf(mA_##sD, acc[3]); }
    for (int c = 0; c < 4; ++c) {
        __syncthreads();
        STAGE(c)
        __syncthreads();
#pragma unroll 2
        for (int nt = 0; nt < 16; ++nt) {
            const int cc = nt * 16 + col;
            const short8v Bhi0 = *(const short8v*)(&eB[cc * EPAD + koff]);
            const short8v Bhi1 = *(const short8v*)(&eB[cc * EPAD + 32 + koff]);
            const float Nc = nB[cc];
            MFMA2A(0, 0, 1, 2, 3) MFMA2A(1, 4, 5, 6, 7)
        }
    }
    // C/D layout: col = l&15 (code), 16-lane groups -> xor 1/2/4/8 butterfly.
#define BFA(s)                                                              \
    mA_##s = fmaxf(mA_##s, __shfl_xor(mA_##s, 1));                          \
    mA_##s = fmaxf(mA_##s, __shfl_xor(mA_##s, 2));                          \
    mA_##s = fmaxf(mA_##s, __shfl_xor(mA_##s, 4));                          \
    mA_##s = fmaxf(mA_##s, __shfl_xor(mA_##s, 8));
    FORSLOT8(BFA)
    // per-slot threshold lives in registers (rows are wave-private)
#define DECL_T(s) const float thr_##s = mA_##s - HDELTA;
    FORSLOT8(DECL_T)
    if (tid < RPB) cnt[tid] = 0;

    // =================== PASS B: candidate collection =======================
#define CHK(s, av)                                                          \
    { if ((av) >= thr_##s) {                                                \
          int row = w * 32 + SLOTROW(s);                                    \
          int pos = atomicAdd(&cnt[row], 1);                                \
          if (pos < 4) clist[row][pos] = code;                              \
      } }
#define MFMA2B(rt, sA, sB, sC, sD)                                          \
    { f32x4 acc = {Nc, Nc, Nc, Nc};                                         \
      acc = __builtin_amdgcn_mfma_f32_16x16x32_bf16(Ahi_##rt##_0, Bhi0, acc, 0, 0, 0); \
      acc = __builtin_amdgcn_mfma_f32_16x16x32_bf16(Ahi_##rt##_1, Bhi1, acc, 0, 0, 0); \
      CHK(sA, acc[0]) CHK(sB, acc[1]) CHK(sC, acc[2]) CHK(sD, acc[3]) }
    for (int c = 0; c < 4; ++c) {
        __syncthreads();
        STAGE(c)
        __syncthreads();
#pragma unroll 2
        for (int nt = 0; nt < 16; ++nt) {
            const int cc = nt * 16 + col;
            const short8v Bhi0 = *(const short8v*)(&eB[cc * EPAD + koff]);
            const short8v Bhi1 = *(const short8v*)(&eB[cc * EPAD + 32 + koff]);
            const float Nc = nB[cc];
            const int code = c * CHUNK + cc;
            MFMA2B(0, 0, 1, 2, 3) MFMA2B(1, 4, 5, 6, 7)
        }
    }
    __syncthreads();

    // ---- select / rescue (1 thread per row), bit-exact final answer ----
    if (tid < RPB) {
        const int row = tid;
        const int n = cnt[row];
        int bk;
        if (n == 1) {
            bk = clist[row][0];
        } else {
            const float* xrow = x + (size_t)(blockrow + row) * D;
            const float R = np_sumsq64(xrow);
            float sb = 3.402823466e+38f;
            int kb = 0x7fffffff;
            if (n <= 4) {
                for (int i = 0; i < n; ++i) {
                    int c = clist[row][i];
                    float s = exact_score(xrow, emb + ((size_t)c << 6), R,
                                          enorm[c]);
                    if (s < sb || (s == sb && c < kb)) { sb = s; kb = c; }
                }
            } else {  // clist overflow: full exact scan (essentially never)
                for (int c = 0; c < K; ++c) {
                    float s = exact_score(xrow, emb + ((size_t)c << 6), R,
                                          enorm[c]);
                    if (s < sb || (s == sb && c < kb)) { sb = s; kb = c; }
                }
            }
            bk = kb;
        }
        bidx[row] = bk;
        idx_f[blockrow + row] = (float)bk;
    }
    __syncthreads();

    // ---- fused epilogue: gather + straight-through + loss (2 rounds) ----
    float lsum = 0.f;
#pragma unroll
    for (int rr = 0; rr < 2; ++rr) {
        const int row = rr * 64 + (tid >> 2);
        const int d0 = (tid & 3) * 16;
        const int bk = bidx[row];
        const float4* xq =
            (const float4*)(x + (size_t)(blockrow + row) * D + d0);
        const float4* eq = (const float4*)(emb + ((size_t)bk << 6) + d0);
        float4* oq = (float4*)(out_q + (size_t)(blockrow + row) * D + d0);
#pragma unroll
        for (int i = 0; i < 4; ++i) {
            float4 xv = xq[i];
            float4 ev = eq[i];
            float dx = ev.x - xv.x, dy = ev.y - xv.y, dz = ev.z - xv.z,
                  dw = ev.w - xv.w;
            float4 o;
            o.x = xv.x + dx;
            o.y = xv.y + dy;
            o.z = xv.z + dz;
            o.w = xv.w + dw;
            oq[i] = o;
            lsum = __builtin_fmaf(dx, dx, lsum);
            lsum = __builtin_fmaf(dy, dy, lsum);
            lsum = __builtin_fmaf(dz, dz, lsum);
            lsum = __builtin_fmaf(dw, dw, lsum);
        }
    }
#pragma unroll
    for (int o = 32; o > 0; o >>= 1) lsum += __shfl_xor(lsum, o);
    if (l == 0) wsum[w] = lsum;
    __syncthreads();
    if (tid == 0)
        atomicAdd(loss_slot, ((wsum[0] + wsum[1]) + (wsum[2] + wsum[3])) *
                                 ((1.0f + COMMIT) / (float)NELEM));
}

extern "C" void kernel_launch(void* const* d_in, const int* in_sizes, int n_in,
                              void* d_out, int out_size, void* d_ws,
                              size_t ws_size, hipStream_t stream) {
    const float* x = (const float*)d_in[0];    // [32,4096,64] f32
    const float* emb = (const float*)d_in[1];  // [1024,64] f32

    float* out = (float*)d_out;
    float* loss_slot = out;              // out[0]
    float* out_q = out + 1;              // out[1 .. 1+NELEM)
    float* idx_f = out + 1 + NELEM;      // indices as f32

    // workspace layout (16B-aligned slabs)
    float* enorm = (float*)d_ws;                                    // 4 KB
    float* enorm_nh = (float*)((char*)d_ws + 4096);                 // 4 KB
    unsigned short* e_hi = (unsigned short*)((char*)d_ws + 8192);   // 128 KB

    prep_emb_kernel<<<(K + 255) / 256, 256, 0, stream>>>(emb, enorm, enorm_nh,
                                                         e_hi, loss_slot);
    argmin_kernel<<<NROWS / RPB, 256, 0, stream>>>(x, emb, enorm, enorm_nh,
                                                   e_hi, out_q, idx_f,
                                                   loss_slot);
}